// Round 5
// baseline (394.117 us; speedup 1.0000x reference)
//
#include <hip/hip_runtime.h>

#define B_ 16
#define N_ 2048
#define IN_ 12
#define H_ 64
#define K_ 16

// Skewed LDS index: row-major [r][k] tiles, stride 68 + 4-float skew per 4 rows.
#define IDX(r, k) ((r) * 68 + ((r) >> 2) * 4 + (k))

// ---------------------------------------------------------------------------
// Kernel A: emb = relu(x@W1+b1)@W2+b2 (one wave per row); sref = 1/max(||e||,eps)
// (byte-identical to round 4 — passing arithmetic, do not modify)
// ---------------------------------------------------------------------------
__global__ __launch_bounds__(256) void emb_kernel(
    const float* __restrict__ x, const float* __restrict__ W1,
    const float* __restrict__ b1, const float* __restrict__ W2,
    const float* __restrict__ b2, float* __restrict__ emb_out,
    float* __restrict__ sref) {
  const int lane = threadIdx.x & 63;
  const int wid = threadIdx.x >> 6;
  const long long row = (long long)blockIdx.x * 4 + wid;  // 0..32767

  const float* xr = x + row * IN_;
  float xv[IN_];
#pragma unroll
  for (int k = 0; k < IN_; ++k) xv[k] = xr[k];

  float acc = b1[lane];
#pragma unroll
  for (int k = 0; k < IN_; ++k) acc += xv[k] * W1[k * H_ + lane];
  float h = fmaxf(acc, 0.f);

  float e = b2[lane];
#pragma unroll
  for (int j = 0; j < H_; ++j) {
    float hj = __shfl(h, j, 64);
    e += hj * W2[j * H_ + lane];
  }

  float ss = e * e;
#pragma unroll
  for (int off = 32; off; off >>= 1) ss += __shfl_xor(ss, off, 64);
  float s = 1.0f / fmaxf(sqrtf(ss), 1e-12f);

  emb_out[row * H_ + lane] = e;
  if (lane == 0) sref[row] = s;
}

// ---------------------------------------------------------------------------
// Kernel B: sim tile GEMM, 128x64 per block, 8x4 outputs/thread.
// (byte-identical to round 4 — passing arithmetic, do not modify)
// ---------------------------------------------------------------------------
__global__ __launch_bounds__(256) void sim_kernel(
    const float* __restrict__ emb, const float* __restrict__ sref,
    float* __restrict__ adj) {
  __shared__ float As[8824];  // IDX(127,63)+1
  __shared__ float Bs[4408];  // IDX(63,63)+1

  const int t = threadIdx.x;
  const int nTj = N_ / 64;                 // 32
  const int tilesPerB = (N_ / 128) * nTj;  // 512
  const int b = blockIdx.x / tilesPerB;
  const int tl = blockIdx.x % tilesPerB;
  const int ti = tl / nTj, tj = tl % nTj;

  const float* Eb = emb + (size_t)b * N_ * H_;
  const float* srb = sref + b * N_;

  // ---- stage A-tile: rows ti*128..+128, pre-scaled by s_i ----
  {
    const int r = t >> 1;              // 0..127
    const int k0 = (t & 1) * 32;       // 0 or 32
    const float sA = srb[ti * 128 + r];
    const float* src = Eb + (size_t)(ti * 128 + r) * H_ + k0;
#pragma unroll
    for (int i = 0; i < 8; ++i) {
      const float4 v = *(const float4*)(src + i * 4);
      float4 w;
      w.x = v.x * sA; w.y = v.y * sA; w.z = v.z * sA; w.w = v.w * sA;
      *(float4*)&As[IDX(r, k0 + i * 4)] = w;
    }
  }
  // ---- stage B-tile: rows tj*64..+64, raw e_j ----
  {
    const int r = t >> 2;              // 0..63
    const int k0 = (t & 3) * 16;
    const float* src = Eb + (size_t)(tj * 64 + r) * H_ + k0;
#pragma unroll
    for (int i = 0; i < 4; ++i) {
      const float4 v = *(const float4*)(src + i * 4);
      *(float4*)&Bs[IDX(r, k0 + i * 4)] = v;
    }
  }
  __syncthreads();

  const int tx = t & 15, ty = t >> 4;
  const int r0 = ty * 8, c0 = tx * 4;

  float4 acc[8][4];
#pragma unroll
  for (int rr = 0; rr < 8; ++rr)
#pragma unroll
    for (int cc = 0; cc < 4; ++cc) acc[rr][cc] = make_float4(0.f, 0.f, 0.f, 0.f);

  int aoff[8], boff[4];
#pragma unroll
  for (int rr = 0; rr < 8; ++rr) aoff[rr] = IDX(r0 + rr, 0);
#pragma unroll
  for (int cc = 0; cc < 4; ++cc) boff[cc] = IDX(c0 + cc, 0);

#pragma unroll 4
  for (int dg = 0; dg < 16; ++dg) {
    float4 av[8], bv[4];
#pragma unroll
    for (int rr = 0; rr < 8; ++rr) av[rr] = *(const float4*)&As[aoff[rr] + dg * 4];
#pragma unroll
    for (int cc = 0; cc < 4; ++cc) bv[cc] = *(const float4*)&Bs[boff[cc] + dg * 4];
#pragma unroll
    for (int rr = 0; rr < 8; ++rr)
#pragma unroll
      for (int cc = 0; cc < 4; ++cc) {
        acc[rr][cc].x += av[rr].x * bv[cc].x;
        acc[rr][cc].y += av[rr].y * bv[cc].y;
        acc[rr][cc].z += av[rr].z * bv[cc].z;
        acc[rr][cc].w += av[rr].w * bv[cc].w;
      }
  }

  // ---- epilogue: (x+y+z+w) * s_j, store ----
  const float4 sjv = *(const float4*)(srb + tj * 64 + c0);
  float* out = adj + (size_t)b * N_ * N_ + (size_t)(ti * 128 + r0) * N_ + tj * 64 + c0;
#pragma unroll
  for (int rr = 0; rr < 8; ++rr) {
    float4 o;
    o.x = (acc[rr][0].x + acc[rr][0].y + acc[rr][0].z + acc[rr][0].w) * sjv.x;
    o.y = (acc[rr][1].x + acc[rr][1].y + acc[rr][1].z + acc[rr][1].w) * sjv.y;
    o.z = (acc[rr][2].x + acc[rr][2].y + acc[rr][2].z + acc[rr][2].w) * sjv.z;
    o.w = (acc[rr][3].x + acc[rr][3].y + acc[rr][3].z + acc[rr][3].w) * sjv.w;
    *(float4*)(out + (size_t)rr * N_) = o;
  }
}

// ---------------------------------------------------------------------------
// Kernel C: in-place top-16 per row. One wave per row, row in registers.
// u64 key = mono(value)<<32 | (N-1-j): same total order as round 4 (value
// desc, index asc == lax.top_k). NEW: per-lane hierarchical group-max cache
// (8 u64 keys, one per float4 group). On pop the owner recomputes only the
// popped group's key (4 slots) + 8-way max, instead of a 32-slot rescan.
// Selection semantics identical to round 4; ~2.5x fewer VALU issues.
// ---------------------------------------------------------------------------
__device__ __forceinline__ unsigned mono32(float v) {
  unsigned u = __float_as_uint(v);
  return u ^ ((unsigned)((int)u >> 31) | 0x80000000u);
}

__global__ __launch_bounds__(256) void topk_kernel(float* __restrict__ adj) {
  const int lane = threadIdx.x & 63;
  const int wid = threadIdx.x >> 6;
  const size_t row = (size_t)blockIdx.x * 4 + wid;  // 0..32767
  float* rp = adj + row * N_;

  // element j = g*256 + lane*4 + c lives in vals[g*4+c]; group g = one float4
  float vals[32];
#pragma unroll
  for (int g = 0; g < 8; ++g) {
    const float4 v = *((const float4*)rp + g * 64 + lane);
    vals[g * 4 + 0] = v.x; vals[g * 4 + 1] = v.y;
    vals[g * 4 + 2] = v.z; vals[g * 4 + 3] = v.w;
  }

  const int jbase = lane * 4;  // within-group element offset for this lane

  // build per-group max keys
  unsigned long long gkey[8];
#pragma unroll
  for (int g = 0; g < 8; ++g) {
    unsigned long long k = 0ull;
#pragma unroll
    for (int c = 0; c < 4; ++c) {
      const int j = g * 256 + jbase + c;
      const unsigned long long key =
          ((unsigned long long)mono32(vals[g * 4 + c]) << 32) |
          (unsigned)(N_ - 1 - j);
      if (key > k) k = key;
    }
    gkey[g] = k;
  }
  unsigned long long lk = 0ull;
#pragma unroll
  for (int g = 0; g < 8; ++g)
    if (gkey[g] > lk) lk = gkey[g];

  unsigned taken = 0u;
  for (int it = 0; it < K_; ++it) {
    unsigned long long bk = lk;
#pragma unroll
    for (int off = 32; off; off >>= 1) {
      const unsigned long long ok = __shfl_xor(bk, off, 64);
      if (ok > bk) bk = ok;
    }
    const int j = N_ - 1 - (int)(bk & 0xFFFFFFFFull);
    if (((j >> 2) & 63) == lane) {           // owner lane pops
      const int g = j >> 8;
      const int slot = (g << 2) | (j & 3);
      taken |= 1u << slot;
      // rebuild only the popped group's key (taken-filtered)
      unsigned long long k = 0ull;
#pragma unroll
      for (int c = 0; c < 4; ++c) {
        const int s2 = (g << 2) | c;
        if (!((taken >> s2) & 1u)) {
          const int jj = (g << 8) + jbase + c;
          const unsigned long long key =
              ((unsigned long long)mono32(vals[s2]) << 32) |
              (unsigned)(N_ - 1 - jj);
          if (key > k) k = key;
        }
      }
      gkey[g] = k;
      // refresh local best over the 8 cached group keys
      unsigned long long nk = 0ull;
#pragma unroll
      for (int gg = 0; gg < 8; ++gg)
        if (gkey[gg] > nk) nk = gkey[gg];
      lk = nk;
    }
  }

  // merged write: winners keep value, everything else zero
#pragma unroll
  for (int g = 0; g < 8; ++g) {
    float4 o;
    o.x = ((taken >> (g * 4 + 0)) & 1u) ? vals[g * 4 + 0] : 0.f;
    o.y = ((taken >> (g * 4 + 1)) & 1u) ? vals[g * 4 + 1] : 0.f;
    o.z = ((taken >> (g * 4 + 2)) & 1u) ? vals[g * 4 + 2] : 0.f;
    o.w = ((taken >> (g * 4 + 3)) & 1u) ? vals[g * 4 + 3] : 0.f;
    *((float4*)rp + g * 64 + lane) = o;
  }
}

extern "C" void kernel_launch(void* const* d_in, const int* in_sizes, int n_in,
                              void* d_out, int out_size, void* d_ws, size_t ws_size,
                              hipStream_t stream) {
  const float* x  = (const float*)d_in[0];
  const float* W1 = (const float*)d_in[1];
  const float* b1 = (const float*)d_in[2];
  const float* W2 = (const float*)d_in[3];
  const float* b2 = (const float*)d_in[4];

  float* adj  = (float*)d_out;                              // B*N*N
  float* embo = (float*)d_out + (size_t)B_ * N_ * N_;       // B*N*H
  float* sref = (float*)d_ws;                               // B*N floats

  emb_kernel<<<(B_ * N_) / 4, 256, 0, stream>>>(x, W1, b1, W2, b2, embo, sref);
  sim_kernel<<<B_ * (N_ / 128) * (N_ / 64), 256, 0, stream>>>(embo, sref, adj);
  topk_kernel<<<(B_ * N_) / 4, 256, 0, stream>>>(adj);
}

// Round 6
// 306.892 us; speedup vs baseline: 1.2842x; 1.2842x over previous
//
#include <hip/hip_runtime.h>

#define B_ 16
#define N_ 2048
#define IN_ 12
#define H_ 64
#define K_ 16

// Skewed LDS index: row-major [r][k] tiles, stride 68 + 4-float skew per 4 rows.
#define IDX(r, k) ((r) * 68 + ((r) >> 2) * 4 + (k))

// ---------------------------------------------------------------------------
// Kernel A: emb = relu(x@W1+b1)@W2+b2 (one wave per row); sref = 1/max(||e||,eps)
// (byte-identical to round 4 — passing arithmetic, do not modify)
// ---------------------------------------------------------------------------
__global__ __launch_bounds__(256) void emb_kernel(
    const float* __restrict__ x, const float* __restrict__ W1,
    const float* __restrict__ b1, const float* __restrict__ W2,
    const float* __restrict__ b2, float* __restrict__ emb_out,
    float* __restrict__ sref) {
  const int lane = threadIdx.x & 63;
  const int wid = threadIdx.x >> 6;
  const long long row = (long long)blockIdx.x * 4 + wid;  // 0..32767

  const float* xr = x + row * IN_;
  float xv[IN_];
#pragma unroll
  for (int k = 0; k < IN_; ++k) xv[k] = xr[k];

  float acc = b1[lane];
#pragma unroll
  for (int k = 0; k < IN_; ++k) acc += xv[k] * W1[k * H_ + lane];
  float h = fmaxf(acc, 0.f);

  float e = b2[lane];
#pragma unroll
  for (int j = 0; j < H_; ++j) {
    float hj = __shfl(h, j, 64);
    e += hj * W2[j * H_ + lane];
  }

  float ss = e * e;
#pragma unroll
  for (int off = 32; off; off >>= 1) ss += __shfl_xor(ss, off, 64);
  float s = 1.0f / fmaxf(sqrtf(ss), 1e-12f);

  emb_out[row * H_ + lane] = e;
  if (lane == 0) sref[row] = s;
}

// ---------------------------------------------------------------------------
// Kernel B: sim tile GEMM, 128x64 per block, 8x4 outputs/thread.
// (byte-identical to round 4 — passing arithmetic, do not modify)
// ---------------------------------------------------------------------------
__global__ __launch_bounds__(256) void sim_kernel(
    const float* __restrict__ emb, const float* __restrict__ sref,
    float* __restrict__ adj) {
  __shared__ float As[8824];  // IDX(127,63)+1
  __shared__ float Bs[4408];  // IDX(63,63)+1

  const int t = threadIdx.x;
  const int nTj = N_ / 64;                 // 32
  const int tilesPerB = (N_ / 128) * nTj;  // 512
  const int b = blockIdx.x / tilesPerB;
  const int tl = blockIdx.x % tilesPerB;
  const int ti = tl / nTj, tj = tl % nTj;

  const float* Eb = emb + (size_t)b * N_ * H_;
  const float* srb = sref + b * N_;

  // ---- stage A-tile: rows ti*128..+128, pre-scaled by s_i ----
  {
    const int r = t >> 1;              // 0..127
    const int k0 = (t & 1) * 32;       // 0 or 32
    const float sA = srb[ti * 128 + r];
    const float* src = Eb + (size_t)(ti * 128 + r) * H_ + k0;
#pragma unroll
    for (int i = 0; i < 8; ++i) {
      const float4 v = *(const float4*)(src + i * 4);
      float4 w;
      w.x = v.x * sA; w.y = v.y * sA; w.z = v.z * sA; w.w = v.w * sA;
      *(float4*)&As[IDX(r, k0 + i * 4)] = w;
    }
  }
  // ---- stage B-tile: rows tj*64..+64, raw e_j ----
  {
    const int r = t >> 2;              // 0..63
    const int k0 = (t & 3) * 16;
    const float* src = Eb + (size_t)(tj * 64 + r) * H_ + k0;
#pragma unroll
    for (int i = 0; i < 4; ++i) {
      const float4 v = *(const float4*)(src + i * 4);
      *(float4*)&Bs[IDX(r, k0 + i * 4)] = v;
    }
  }
  __syncthreads();

  const int tx = t & 15, ty = t >> 4;
  const int r0 = ty * 8, c0 = tx * 4;

  float4 acc[8][4];
#pragma unroll
  for (int rr = 0; rr < 8; ++rr)
#pragma unroll
    for (int cc = 0; cc < 4; ++cc) acc[rr][cc] = make_float4(0.f, 0.f, 0.f, 0.f);

  int aoff[8], boff[4];
#pragma unroll
  for (int rr = 0; rr < 8; ++rr) aoff[rr] = IDX(r0 + rr, 0);
#pragma unroll
  for (int cc = 0; cc < 4; ++cc) boff[cc] = IDX(c0 + cc, 0);

#pragma unroll 4
  for (int dg = 0; dg < 16; ++dg) {
    float4 av[8], bv[4];
#pragma unroll
    for (int rr = 0; rr < 8; ++rr) av[rr] = *(const float4*)&As[aoff[rr] + dg * 4];
#pragma unroll
    for (int cc = 0; cc < 4; ++cc) bv[cc] = *(const float4*)&Bs[boff[cc] + dg * 4];
#pragma unroll
    for (int rr = 0; rr < 8; ++rr)
#pragma unroll
      for (int cc = 0; cc < 4; ++cc) {
        acc[rr][cc].x += av[rr].x * bv[cc].x;
        acc[rr][cc].y += av[rr].y * bv[cc].y;
        acc[rr][cc].z += av[rr].z * bv[cc].z;
        acc[rr][cc].w += av[rr].w * bv[cc].w;
      }
  }

  // ---- epilogue: (x+y+z+w) * s_j, store ----
  const float4 sjv = *(const float4*)(srb + tj * 64 + c0);
  float* out = adj + (size_t)b * N_ * N_ + (size_t)(ti * 128 + r0) * N_ + tj * 64 + c0;
#pragma unroll
  for (int rr = 0; rr < 8; ++rr) {
    float4 o;
    o.x = (acc[rr][0].x + acc[rr][0].y + acc[rr][0].z + acc[rr][0].w) * sjv.x;
    o.y = (acc[rr][1].x + acc[rr][1].y + acc[rr][1].z + acc[rr][1].w) * sjv.y;
    o.z = (acc[rr][2].x + acc[rr][2].y + acc[rr][2].z + acc[rr][2].w) * sjv.z;
    o.w = (acc[rr][3].x + acc[rr][3].y + acc[rr][3].z + acc[rr][3].w) * sjv.w;
    *(float4*)(out + (size_t)rr * N_) = o;
  }
}

// ---------------------------------------------------------------------------
// Kernel C: in-place top-16 per row. One wave per row, row in registers.
// u64 key = mono(value)<<32 | (N-1-j): value desc, index asc (lax.top_k).
// Hierarchical group-max cache in 8 NAMED u64 registers (gk0..gk7). The
// butterfly winner j is wave-uniform -> uniform switch(g) with statically
// indexed case arms; no runtime-indexed arrays, no scratch (fixes round 5).
// ---------------------------------------------------------------------------
__device__ __forceinline__ unsigned mono32(float v) {
  unsigned u = __float_as_uint(v);
  return u ^ ((unsigned)((int)u >> 31) | 0x80000000u);
}

// Build the max key over group G's remaining (not-taken) slots. All indices
// compile-time constants.
#define GKEY_BUILD(G, DST)                                                  \
  {                                                                         \
    unsigned long long k2 = 0ull;                                           \
    _Pragma("unroll") for (int c = 0; c < 4; ++c) {                         \
      const int s2 = ((G) << 2) | c;                                        \
      if (!((taken >> s2) & 1u)) {                                          \
        const int jj = ((G) << 8) + (lane << 2) + c;                        \
        const unsigned long long key =                                      \
            ((unsigned long long)mono32(vals[s2]) << 32) |                  \
            (unsigned)(N_ - 1 - jj);                                        \
        if (key > k2) k2 = key;                                             \
      }                                                                     \
    }                                                                       \
    DST = k2;                                                               \
  }

__global__ __launch_bounds__(256) void topk_kernel(float* __restrict__ adj) {
  const int lane = threadIdx.x & 63;
  const int wid = threadIdx.x >> 6;
  const size_t row = (size_t)blockIdx.x * 4 + wid;  // 0..32767
  float* rp = adj + row * N_;

  // element j = g*256 + lane*4 + c lives in vals[g*4+c]
  float vals[32];
#pragma unroll
  for (int g = 0; g < 8; ++g) {
    const float4 v = *((const float4*)rp + g * 64 + lane);
    vals[g * 4 + 0] = v.x; vals[g * 4 + 1] = v.y;
    vals[g * 4 + 2] = v.z; vals[g * 4 + 3] = v.w;
  }

  unsigned taken = 0u;
  unsigned long long gk0, gk1, gk2, gk3, gk4, gk5, gk6, gk7;
  GKEY_BUILD(0, gk0); GKEY_BUILD(1, gk1); GKEY_BUILD(2, gk2); GKEY_BUILD(3, gk3);
  GKEY_BUILD(4, gk4); GKEY_BUILD(5, gk5); GKEY_BUILD(6, gk6); GKEY_BUILD(7, gk7);

#define LK_REFRESH()                                                        \
  lk = gk0;                                                                 \
  if (gk1 > lk) lk = gk1;                                                   \
  if (gk2 > lk) lk = gk2;                                                   \
  if (gk3 > lk) lk = gk3;                                                   \
  if (gk4 > lk) lk = gk4;                                                   \
  if (gk5 > lk) lk = gk5;                                                   \
  if (gk6 > lk) lk = gk6;                                                   \
  if (gk7 > lk) lk = gk7

  unsigned long long lk;
  LK_REFRESH();

  for (int it = 0; it < K_; ++it) {
    unsigned long long bk = lk;
#pragma unroll
    for (int off = 32; off; off >>= 1) {
      const unsigned long long ok = __shfl_xor(bk, off, 64);
      if (ok > bk) bk = ok;
    }
    // bk (hence j, g, owner) is wave-uniform
    const int j = N_ - 1 - (int)(bk & 0xFFFFFFFFull);
    const bool own = ((j >> 2) & 63) == lane;
    const int g = j >> 8;
    if (own) taken |= 1u << ((g << 2) | (j & 3));
    switch (g) {  // uniform branch; static register indexing in each arm
      case 0: if (own) GKEY_BUILD(0, gk0); break;
      case 1: if (own) GKEY_BUILD(1, gk1); break;
      case 2: if (own) GKEY_BUILD(2, gk2); break;
      case 3: if (own) GKEY_BUILD(3, gk3); break;
      case 4: if (own) GKEY_BUILD(4, gk4); break;
      case 5: if (own) GKEY_BUILD(5, gk5); break;
      case 6: if (own) GKEY_BUILD(6, gk6); break;
      default: if (own) GKEY_BUILD(7, gk7); break;
    }
    LK_REFRESH();
  }

  // merged write: winners keep value, everything else zero
#pragma unroll
  for (int g2 = 0; g2 < 8; ++g2) {
    float4 o;
    o.x = ((taken >> (g2 * 4 + 0)) & 1u) ? vals[g2 * 4 + 0] : 0.f;
    o.y = ((taken >> (g2 * 4 + 1)) & 1u) ? vals[g2 * 4 + 1] : 0.f;
    o.z = ((taken >> (g2 * 4 + 2)) & 1u) ? vals[g2 * 4 + 2] : 0.f;
    o.w = ((taken >> (g2 * 4 + 3)) & 1u) ? vals[g2 * 4 + 3] : 0.f;
    *((float4*)rp + g2 * 64 + lane) = o;
  }
}

extern "C" void kernel_launch(void* const* d_in, const int* in_sizes, int n_in,
                              void* d_out, int out_size, void* d_ws, size_t ws_size,
                              hipStream_t stream) {
  const float* x  = (const float*)d_in[0];
  const float* W1 = (const float*)d_in[1];
  const float* b1 = (const float*)d_in[2];
  const float* W2 = (const float*)d_in[3];
  const float* b2 = (const float*)d_in[4];

  float* adj  = (float*)d_out;                              // B*N*N
  float* embo = (float*)d_out + (size_t)B_ * N_ * N_;       // B*N*H
  float* sref = (float*)d_ws;                               // B*N floats

  emb_kernel<<<(B_ * N_) / 4, 256, 0, stream>>>(x, W1, b1, W2, b2, embo, sref);
  sim_kernel<<<B_ * (N_ / 128) * (N_ / 64), 256, 0, stream>>>(embo, sref, adj);
  topk_kernel<<<(B_ * N_) / 4, 256, 0, stream>>>(adj);
}